// Round 1
// baseline (2647.131 us; speedup 1.0000x reference)
//
#include <hip/hip_runtime.h>
#include <hip/hip_bf16.h>

typedef __bf16 bf16x8 __attribute__((ext_vector_type(8)));
typedef float  f32x4  __attribute__((ext_vector_type(4)));

#define T_TOK 4096
#define HDIM  2048
#define NEXP  32
#define TOPK  4
#define FDIM  1408
#define F2DIM 2816
#define FSDIM 5632
#define FS2DIM 11264
#define RPAD  16512   // 16384 dispatched rows + 128 slack rows for tile overrun

__device__ __forceinline__ unsigned short f2bfu(float x){ return __builtin_bit_cast(unsigned short, (__bf16)x); }
__device__ __forceinline__ float bfu2f(unsigned short u){ return (float)__builtin_bit_cast(__bf16, u); }
__device__ __forceinline__ ushort4 pack4(float4 v){
  ushort4 o; o.x=f2bfu(v.x); o.y=f2bfu(v.y); o.z=f2bfu(v.z); o.w=f2bfu(v.w); return o;
}

// async global->LDS, 16B per lane; LDS dest = base + lane*16 (wave-uniform base)
__device__ __forceinline__ void g2l16(const void* g, void* l){
  __builtin_amdgcn_global_load_lds((const __attribute__((address_space(1))) unsigned int*)g,
                                   (__attribute__((address_space(3))) unsigned int*)l, 16, 0, 0);
}

// ---------------------------------------------------------------------------
// Weight swizzle: fp32 KxN row-major -> bf16 frag-ready [N/16][K/32][lane64][8]
// frag content: lane l, j: W[k32*32 + (l>>4)*8 + j][n16*16 + (l&15)]
// ---------------------------------------------------------------------------
__global__ void swz_k(const float* __restrict__ W, __bf16* __restrict__ O, int K, int N){
  const int k32c = K >> 5;
  const size_t mat = (size_t)K * N;
  const float* Wm = W + blockIdx.y * mat;
  __bf16* Om = O + blockIdx.y * mat;
  const int fid = blockIdx.x * 256 + threadIdx.x;
  const int l = fid & 63, q = fid >> 6;
  const int k32 = q % k32c, n16 = q / k32c;
  const float* src = Wm + (size_t)(k32*32 + ((l>>4)<<3)) * N + n16*16 + (l & 15);
  bf16x8 v;
  #pragma unroll
  for (int j=0;j<8;j++) v[j] = (__bf16)src[(size_t)j * N];
  *(bf16x8*)(Om + (size_t)fid * 8) = v;
}

// ---------------------------------------------------------------------------
// Router: fp64 logits -> softmax -> top-4 (lowest-index tie-break), histogram
// ---------------------------------------------------------------------------
__global__ __launch_bounds__(256) void router_k(const float* __restrict__ hs, const float* __restrict__ rwgt,
    float* __restrict__ rwo, int* __restrict__ idxo, int* __restrict__ counts){
  __shared__ float sh[4][HDIM];
  __shared__ double lg[4][NEXP];
  const int tid = threadIdx.x;
  const int tok0 = blockIdx.x * 4;
  {
    const float4* src = (const float4*)(hs + (size_t)tok0 * HDIM);
    float4* d = (float4*)sh;
    #pragma unroll
    for (int i=0;i<8;i++) d[tid + i*256] = src[tid + i*256];
  }
  __syncthreads();
  const int e = tid >> 3, s = tid & 7;
  double a0=0.0,a1=0.0,a2=0.0,a3=0.0;
  const float* wr = rwgt + e * HDIM;
  for (int hh=0; hh<256; hh++){
    const int h = s + hh*8;
    const double wv = (double)wr[h];
    a0 += wv * (double)sh[0][h];
    a1 += wv * (double)sh[1][h];
    a2 += wv * (double)sh[2][h];
    a3 += wv * (double)sh[3][h];
  }
  #pragma unroll
  for (int d=4; d>=1; d>>=1){
    a0 += __shfl_down(a0, d, 8);
    a1 += __shfl_down(a1, d, 8);
    a2 += __shfl_down(a2, d, 8);
    a3 += __shfl_down(a3, d, 8);
  }
  if (s == 0){ lg[0][e]=a0; lg[1][e]=a1; lg[2][e]=a2; lg[3][e]=a3; }
  __syncthreads();
  if (tid < 128){
    const int r = tid >> 5, ee = tid & 31;
    const double lv = lg[r][ee];
    double mx = lv;
    #pragma unroll
    for (int d=16; d>=1; d>>=1) mx = fmax(mx, __shfl_xor(mx, d, 32));
    double p = exp(lv - mx);
    double sum = p;
    #pragma unroll
    for (int d=16; d>=1; d>>=1) sum += __shfl_xor(sum, d, 32);
    p /= sum;
    double v = p;
    for (int k=0;k<4;k++){
      double bv = v; int bi = ee;
      #pragma unroll
      for (int d=16; d>=1; d>>=1){
        const double ov = __shfl_xor(bv, d, 32);
        const int    oi = __shfl_xor(bi, d, 32);
        if (ov > bv || (ov == bv && oi < bi)){ bv = ov; bi = oi; }
      }
      if (ee == 0){
        const int t = tok0 + r;
        rwo[t*TOPK + k] = (float)bv;
        idxo[t*TOPK + k] = bi;
        atomicAdd(counts + bi, 1);
      }
      if (ee == bi) v = -1.0;
    }
  }
}

__global__ void scan_k(const int* __restrict__ counts, int* __restrict__ seg){
  if (threadIdx.x == 0){
    int off = 0;
    for (int e=0;e<NEXP;e++){ seg[e] = off; off += counts[e]; }
  }
}

// one wave per (token,slot): place row + copy hidden row to bf16 dispatch buffer
__global__ void dispatch_k(const float* __restrict__ hs, const int* __restrict__ idxo,
    const float* __restrict__ rwo, const int* __restrict__ seg, int* __restrict__ ctr,
    int* __restrict__ srctok, float* __restrict__ roww, __bf16* __restrict__ Adisp){
  const int slot = blockIdx.x;
  const int l = threadIdx.x;
  const int t = slot >> 2;
  int p = 0;
  if (l == 0){
    const int ex = idxo[slot];
    p = seg[ex] + atomicAdd(ctr + ex, 1);
    srctok[p] = t;
    roww[p] = rwo[slot];
  }
  p = __shfl(p, 0, 64);
  const float4* src = (const float4*)(hs + (size_t)t * HDIM);
  ushort4* dst = (ushort4*)(Adisp + (size_t)p * HDIM);
  #pragma unroll
  for (int i=0;i<8;i++) dst[l + i*64] = pack4(src[l + i*64]);
}

__global__ void cvt_bf16_k(const float* __restrict__ src, __bf16* __restrict__ dst, int total4){
  const int idx = blockIdx.x*256 + threadIdx.x;
  if (idx >= total4) return;
  ((ushort4*)dst)[idx] = pack4(((const float4*)src)[idx]);
}

__global__ void sgate_k(const float* __restrict__ hs, const float* __restrict__ gw, float* __restrict__ sg){
  const int t = blockIdx.x, l = threadIdx.x;
  const float4* r = (const float4*)(hs + (size_t)t*HDIM);
  const float4* g = (const float4*)gw;
  float s = 0.f;
  #pragma unroll
  for (int i=0;i<8;i++){
    const float4 a = r[l + i*64]; const float4 b = g[l + i*64];
    s += a.x*b.x + a.y*b.y + a.z*b.z + a.w*b.w;
  }
  #pragma unroll
  for (int d=32; d>=1; d>>=1) s += __shfl_xor(s, d, 64);
  if (l==0) sg[t] = 1.f/(1.f + expf(-s));
}

__global__ void swiglu_k(const __bf16* __restrict__ m, __bf16* __restrict__ a,
                         long long total4, int F, int F2){
  const long long idx = (long long)blockIdx.x * 256 + threadIdx.x;
  if (idx >= total4) return;
  const int f4 = F >> 2;
  const int r = (int)(idx / f4);
  const int c = (int)(idx % f4);
  const ushort4 g4 = *(const ushort4*)(m + (size_t)r * F2 + c*4);
  const ushort4 u4 = *(const ushort4*)(m + (size_t)r * F2 + F + c*4);
  const float gf0=bfu2f(g4.x), gf1=bfu2f(g4.y), gf2=bfu2f(g4.z), gf3=bfu2f(g4.w);
  const float uf0=bfu2f(u4.x), uf1=bfu2f(u4.y), uf2=bfu2f(u4.z), uf3=bfu2f(u4.w);
  ushort4 o;
  o.x = f2bfu(gf0/(1.f+expf(-gf0))*uf0);
  o.y = f2bfu(gf1/(1.f+expf(-gf1))*uf1);
  o.z = f2bfu(gf2/(1.f+expf(-gf2))*uf2);
  o.w = f2bfu(gf3/(1.f+expf(-gf3))*uf3);
  *(ushort4*)(a + (size_t)r * F + c*4) = o;
}

// ---------------------------------------------------------------------------
// 128x128 bf16 MFMA GEMM, BK=32, 256 threads (4 waves, each 32m x 128n).
// A: row-major bf16 MxK. B: frag-swizzled bf16 (per-expert). Ragged via seg/cnt.
// MODE 0: store bf16 C. MODE 1: atomicAdd(out[srctok]*roww). MODE 2: atomicAdd(out*sgate).
// ---------------------------------------------------------------------------
template<int MODE>
__global__ __launch_bounds__(256) void gemm_sw(
    const __bf16* __restrict__ A, const __bf16* __restrict__ Bsw,
    int K, int N, int Mdense,
    const int* __restrict__ seg0, const int* __restrict__ segc,
    __bf16* __restrict__ Cb, int ldc,
    float* __restrict__ Cf,
    const int* __restrict__ src_tok, const float* __restrict__ row_w,
    const float* __restrict__ sgate)
{
  __shared__ __align__(16) __bf16 As[4096];  // 128 rows x 32 (64B/row)
  __shared__ __align__(16) __bf16 Bs[4096];  // 8 n-groups x 1KB frag-packed
  const int tid = threadIdx.x;
  const int w = tid >> 6, l = tid & 63;
  const int e = blockIdx.z;
  const int row0 = seg0 ? seg0[e] : 0;
  const int cnt  = seg0 ? segc[e] : Mdense;
  const int n0 = blockIdx.x * 128;
  const int K32 = K >> 5;
  const __bf16* Be = Bsw + (size_t)e * ((size_t)K * N);

  for (int mt = blockIdx.y; mt * 128 < cnt; mt += gridDim.y) {
    const __bf16* Am = A + (size_t)(row0 + mt * 128) * K;
    f32x4 acc[2][8];
    #pragma unroll
    for (int i = 0; i < 2; i++)
      #pragma unroll
      for (int g = 0; g < 8; g++) acc[i][g] = (f32x4){0.f,0.f,0.f,0.f};

    for (int k0 = 0; k0 < K; k0 += 32) {
      __syncthreads();
      #pragma unroll
      for (int q = 0; q < 2; q++) {
        const int inst = w * 2 + q;
        const int arow = inst * 16 + (l >> 2);
        g2l16(Am + (size_t)arow * K + k0 + (l & 3) * 8, As + inst * 512);
        g2l16(Be + ((size_t)(n0/16 + inst) * K32 + (k0 >> 5)) * 512 + l * 8, Bs + inst * 512);
      }
      __syncthreads();
      bf16x8 af[2], bfr[8];
      #pragma unroll
      for (int i = 0; i < 2; i++)
        af[i] = *(const bf16x8*)(As + (w*32 + i*16 + (l & 15)) * 32 + (l >> 4) * 8);
      #pragma unroll
      for (int g = 0; g < 8; g++)
        bfr[g] = *(const bf16x8*)(Bs + g * 512 + l * 8);
      #pragma unroll
      for (int i = 0; i < 2; i++)
        #pragma unroll
        for (int g = 0; g < 8; g++)
          acc[i][g] = __builtin_amdgcn_mfma_f32_16x16x32_bf16(af[i], bfr[g], acc[i][g], 0, 0, 0);
    }
    const int rows_left = cnt - mt * 128;
    #pragma unroll
    for (int i = 0; i < 2; i++) {
      const int rb = w * 32 + i * 16 + (l >> 4) * 4;
      #pragma unroll
      for (int r = 0; r < 4; r++) {
        const int lr = rb + r;
        if (lr < rows_left) {
          const int grow = row0 + mt * 128 + lr;
          if (MODE == 0) {
            #pragma unroll
            for (int g = 0; g < 8; g++)
              Cb[(size_t)grow * ldc + n0 + g * 16 + (l & 15)] = (__bf16)acc[i][g][r];
          } else if (MODE == 1) {
            const int t = src_tok[grow];
            const float wgt = row_w[grow];
            #pragma unroll
            for (int g = 0; g < 8; g++)
              atomicAdd(Cf + (size_t)t * HDIM + n0 + g * 16 + (l & 15), wgt * acc[i][g][r]);
          } else {
            const float wgt = sgate[grow];
            #pragma unroll
            for (int g = 0; g < 8; g++)
              atomicAdd(Cf + (size_t)grow * HDIM + n0 + g * 16 + (l & 15), wgt * acc[i][g][r]);
          }
        }
      }
    }
  }
}

// ---------------------------------------------------------------------------
extern "C" void kernel_launch(void* const* d_in, const int* in_sizes, int n_in,
                              void* d_out, int out_size, void* d_ws, size_t ws_size,
                              hipStream_t stream){
  const float* hs   = (const float*)d_in[0];
  const float* rwgt = (const float*)d_in[1];
  const float* gu   = (const float*)d_in[2];
  const float* dn   = (const float*)d_in[3];
  const float* sgu  = (const float*)d_in[4];
  const float* sdn  = (const float*)d_in[5];
  const float* gw   = (const float*)d_in[6];
  float* out = (float*)d_out;
  (void)in_sizes; (void)n_in; (void)out_size;

  char* wbase = (char*)d_ws;
  size_t off = 0;
  auto alloc = [&](size_t bytes)->char*{ char* p = wbase + off; off += (bytes + 255) & ~(size_t)255; return p; };
  __bf16* gu_sw  = (__bf16*)alloc((size_t)NEXP*HDIM*F2DIM*2);
  __bf16* dn_sw  = (__bf16*)alloc((size_t)NEXP*FDIM*HDIM*2);
  __bf16* sgu_sw = (__bf16*)alloc((size_t)HDIM*FS2DIM*2);
  __bf16* sdn_sw = (__bf16*)alloc((size_t)FSDIM*HDIM*2);
  __bf16* Adisp  = (__bf16*)alloc((size_t)RPAD*HDIM*2);
  __bf16* act    = (__bf16*)alloc((size_t)RPAD*FDIM*2);     // reused as shared act [4096][5632]
  __bf16* merged = (__bf16*)alloc((size_t)RPAD*F2DIM*2);    // reused as shared merged [4096][11264]
  __bf16* hsbf   = (__bf16*)alloc((size_t)T_TOK*HDIM*2);
  float* rwo     = (float*)alloc((size_t)T_TOK*TOPK*4);
  int*   idxo    = (int*)  alloc((size_t)T_TOK*TOPK*4);
  int*   srctok  = (int*)  alloc((size_t)RPAD*4);
  float* roww    = (float*)alloc((size_t)RPAD*4);
  float* sgate   = (float*)alloc((size_t)T_TOK*4);
  int*   meta    = (int*)  alloc(384);
  int* counts = meta; int* seg = meta + 32; int* ctr = meta + 64;

  if (ws_size < off){  // workspace too small: bail (output stays zero -> distinctive absmax)
    hipMemsetAsync(out, 0, (size_t)T_TOK*HDIM*4, stream);
    return;
  }

  hipMemsetAsync(meta, 0, 384, stream);
  hipMemsetAsync(out, 0, (size_t)T_TOK*HDIM*4, stream);

  // weight fp32 -> bf16 frag-swizzle
  swz_k<<<dim3(2816, NEXP), 256, 0, stream>>>(gu,  gu_sw,  HDIM,  F2DIM);
  swz_k<<<dim3(1408, NEXP), 256, 0, stream>>>(dn,  dn_sw,  FDIM,  HDIM);
  swz_k<<<dim3(11264, 1),  256, 0, stream>>>(sgu, sgu_sw, HDIM,  FS2DIM);
  swz_k<<<dim3(5632, 1),   256, 0, stream>>>(sdn, sdn_sw, FSDIM, HDIM);

  router_k<<<T_TOK/4, 256, 0, stream>>>(hs, rwgt, rwo, idxo, counts);
  scan_k<<<1, 64, 0, stream>>>(counts, seg);
  dispatch_k<<<T_TOK*TOPK, 64, 0, stream>>>(hs, idxo, rwo, seg, ctr, srctok, roww, Adisp);
  cvt_bf16_k<<<(T_TOK*HDIM/4 + 255)/256, 256, 0, stream>>>(hs, hsbf, T_TOK*HDIM/4);
  sgate_k<<<T_TOK, 64, 0, stream>>>(hs, gw, sgate);

  // shared-expert path (uses merged/act regions first)
  gemm_sw<0><<<dim3(FS2DIM/128, T_TOK/128, 1), 256, 0, stream>>>(
      hsbf, sgu_sw, HDIM, FS2DIM, T_TOK, nullptr, nullptr,
      merged, FS2DIM, nullptr, nullptr, nullptr, nullptr);
  {
    long long tot4 = (long long)T_TOK * FSDIM / 4;
    swiglu_k<<<(unsigned)((tot4 + 255)/256), 256, 0, stream>>>(merged, act, tot4, FSDIM, FS2DIM);
  }
  gemm_sw<2><<<dim3(HDIM/128, T_TOK/128, 1), 256, 0, stream>>>(
      act, sdn_sw, FSDIM, HDIM, T_TOK, nullptr, nullptr,
      nullptr, 0, out, nullptr, nullptr, sgate);

  // MoE expert path (ragged over 32 expert segments)
  gemm_sw<0><<<dim3(F2DIM/128, 8, NEXP), 256, 0, stream>>>(
      Adisp, gu_sw, HDIM, F2DIM, 0, seg, counts,
      merged, F2DIM, nullptr, nullptr, nullptr, nullptr);
  {
    long long tot4 = (long long)RPAD * FDIM / 4;
    swiglu_k<<<(unsigned)((tot4 + 255)/256), 256, 0, stream>>>(merged, act, tot4, FDIM, F2DIM);
  }
  gemm_sw<1><<<dim3(HDIM/128, 8, NEXP), 256, 0, stream>>>(
      act, dn_sw, FDIM, HDIM, 0, seg, counts,
      nullptr, 0, out, srctok, roww, nullptr);
}